// Round 1
// baseline (500.349 us; speedup 1.0000x reference)
//
#include <hip/hip_runtime.h>

// Segment mean: out[n,:] = mean over e[i,:] where dst[i]==n; 0 if no in-edges.
// E=1.6M, D=32, N=100k.
// Pipeline (counting sort -> CSR -> gather, no big-LDS staging):
//   memset cnt -> hist (global atomics, 400KB L2-resident)
//   -> 3-kernel exclusive scan of cnt into start/run
//   -> scatter: ids[atomicAdd(run[dst])] = edge   (6.4MB, L2-absorbable)
//   -> gather: 8 lanes/node, 8-deep unrolled random 128B row reads.

#define D_FEAT 32
#define SCAN_SPAN 1024   // elements per scan block (256 threads * int4)

// ---------------- hist: cnt[n] = in-degree ----------------
__global__ __launch_bounds__(256) void hist_kernel(
    const int* __restrict__ dst, int* __restrict__ cnt, int E)
{
    int base = (blockIdx.x * 256 + threadIdx.x) * 4;
    if (base + 3 < E) {
        int4 d = *(const int4*)(dst + base);
        atomicAdd(&cnt[d.x], 1);
        atomicAdd(&cnt[d.y], 1);
        atomicAdd(&cnt[d.z], 1);
        atomicAdd(&cnt[d.w], 1);
    } else {
        for (int i = base; i < E; i++) atomicAdd(&cnt[dst[i]], 1);
    }
}

// ---------------- scan step 1: per-block sums ----------------
__global__ __launch_bounds__(256) void scan_block_sums(
    const int* __restrict__ cnt, int* __restrict__ bsum, int N)
{
    __shared__ int red[256];
    int t = threadIdx.x;
    int base = blockIdx.x * SCAN_SPAN + t * 4;
    int s = 0;
    if (base + 3 < N) {
        int4 v = *(const int4*)(cnt + base);
        s = v.x + v.y + v.z + v.w;
    } else {
        for (int i = base; i < N; i++) s += cnt[i];
    }
    red[t] = s;
    __syncthreads();
    for (int off = 128; off > 0; off >>= 1) {
        if (t < off) red[t] += red[t + off];
        __syncthreads();
    }
    if (t == 0) bsum[blockIdx.x] = red[0];
}

// ---------------- scan step 2: exclusive scan of block sums (1 block) ----------------
__global__ __launch_bounds__(256) void scan_bases(
    const int* __restrict__ bsum, int* __restrict__ bbase, int nblk)
{
    __shared__ int sc[256];
    int t = threadIdx.x;
    int v = (t < nblk) ? bsum[t] : 0;
    int orig = v;
    sc[t] = v;
    __syncthreads();
    for (int off = 1; off < 256; off <<= 1) {
        int u = (t >= off) ? sc[t - off] : 0;
        __syncthreads();
        sc[t] += u;
        __syncthreads();
    }
    if (t < nblk) bbase[t] = sc[t] - orig;    // exclusive
}

// ---------------- scan step 3: write start[] and run[] ----------------
__global__ __launch_bounds__(256) void scan_write(
    const int* __restrict__ cnt, const int* __restrict__ bbase,
    int* __restrict__ startArr, int* __restrict__ run, int N)
{
    __shared__ int sc[256];
    int t = threadIdx.x;
    int base = blockIdx.x * SCAN_SPAN + t * 4;
    int c0 = 0, c1 = 0, c2 = 0, c3 = 0;
    if (base + 3 < N) {
        int4 v = *(const int4*)(cnt + base);
        c0 = v.x; c1 = v.y; c2 = v.z; c3 = v.w;
    } else {
        if (base     < N) c0 = cnt[base];
        if (base + 1 < N) c1 = cnt[base + 1];
        if (base + 2 < N) c2 = cnt[base + 2];
        if (base + 3 < N) c3 = cnt[base + 3];
    }
    int s = c0 + c1 + c2 + c3;
    int orig = s;
    sc[t] = s;
    __syncthreads();
    for (int off = 1; off < 256; off <<= 1) {
        int u = (t >= off) ? sc[t - off] : 0;
        __syncthreads();
        sc[t] += u;
        __syncthreads();
    }
    int ex = bbase[blockIdx.x] + sc[t] - orig;
    int p0 = ex, p1 = ex + c0, p2 = p1 + c1, p3 = p2 + c2;
    if (base + 3 < N) {
        *(int4*)(startArr + base) = make_int4(p0, p1, p2, p3);
        *(int4*)(run + base)      = make_int4(p0, p1, p2, p3);
    } else {
        if (base     < N) { startArr[base]     = p0; run[base]     = p0; }
        if (base + 1 < N) { startArr[base + 1] = p1; run[base + 1] = p1; }
        if (base + 2 < N) { startArr[base + 2] = p2; run[base + 2] = p2; }
        if (base + 3 < N) { startArr[base + 3] = p3; run[base + 3] = p3; }
    }
}

// ---------------- scatter: node-sorted edge-id CSR ----------------
__global__ __launch_bounds__(256) void scatter_kernel(
    const int* __restrict__ dst, int* __restrict__ run,
    unsigned int* __restrict__ ids, int E)
{
    int base = (blockIdx.x * 256 + threadIdx.x) * 4;
    if (base + 3 < E) {
        int4 d = *(const int4*)(dst + base);
        int p0 = atomicAdd(&run[d.x], 1);
        int p1 = atomicAdd(&run[d.y], 1);
        int p2 = atomicAdd(&run[d.z], 1);
        int p3 = atomicAdd(&run[d.w], 1);
        ids[p0] = (unsigned)base;
        ids[p1] = (unsigned)base + 1;
        ids[p2] = (unsigned)base + 2;
        ids[p3] = (unsigned)base + 3;
    } else {
        for (int i = base; i < E; i++)
            ids[atomicAdd(&run[dst[i]], 1)] = (unsigned)i;
    }
}

// ---------------- gather: 8 lanes/node, 8-deep MLP ----------------
__global__ __launch_bounds__(256) void gather_kernel(
    const float4* __restrict__ e4,            // [E*8]
    const unsigned int* __restrict__ ids,
    const int* __restrict__ startArr,
    const int* __restrict__ cntArr,
    float4* __restrict__ out4,                // [N*8]
    int N)
{
    int node = blockIdx.x * 32 + (threadIdx.x >> 3);
    int j = threadIdx.x & 7;
    if (node >= N) return;
    int c = cntArr[node];
    int s = startArr[node];
    float4 a0 = {0.f,0.f,0.f,0.f}, a1 = {0.f,0.f,0.f,0.f};
    float4 a2 = {0.f,0.f,0.f,0.f}, a3 = {0.f,0.f,0.f,0.f};
    int k = 0;
    for (; k + 8 <= c; k += 8) {
        unsigned e0 = ids[s+k],   e1 = ids[s+k+1], e2 = ids[s+k+2], e3 = ids[s+k+3];
        unsigned e4i = ids[s+k+4], e5 = ids[s+k+5], e6 = ids[s+k+6], e7 = ids[s+k+7];
        float4 v0 = e4[(size_t)e0*8  + j];
        float4 v1 = e4[(size_t)e1*8  + j];
        float4 v2 = e4[(size_t)e2*8  + j];
        float4 v3 = e4[(size_t)e3*8  + j];
        float4 v4 = e4[(size_t)e4i*8 + j];
        float4 v5 = e4[(size_t)e5*8  + j];
        float4 v6 = e4[(size_t)e6*8  + j];
        float4 v7 = e4[(size_t)e7*8  + j];
        a0.x += v0.x; a0.y += v0.y; a0.z += v0.z; a0.w += v0.w;
        a1.x += v1.x; a1.y += v1.y; a1.z += v1.z; a1.w += v1.w;
        a2.x += v2.x; a2.y += v2.y; a2.z += v2.z; a2.w += v2.w;
        a3.x += v3.x; a3.y += v3.y; a3.z += v3.z; a3.w += v3.w;
        a0.x += v4.x; a0.y += v4.y; a0.z += v4.z; a0.w += v4.w;
        a1.x += v5.x; a1.y += v5.y; a1.z += v5.z; a1.w += v5.w;
        a2.x += v6.x; a2.y += v6.y; a2.z += v6.z; a2.w += v6.w;
        a3.x += v7.x; a3.y += v7.y; a3.z += v7.z; a3.w += v7.w;
    }
    for (; k + 4 <= c; k += 4) {
        unsigned e0 = ids[s+k], e1 = ids[s+k+1], e2 = ids[s+k+2], e3 = ids[s+k+3];
        float4 v0 = e4[(size_t)e0*8 + j];
        float4 v1 = e4[(size_t)e1*8 + j];
        float4 v2 = e4[(size_t)e2*8 + j];
        float4 v3 = e4[(size_t)e3*8 + j];
        a0.x += v0.x; a0.y += v0.y; a0.z += v0.z; a0.w += v0.w;
        a1.x += v1.x; a1.y += v1.y; a1.z += v1.z; a1.w += v1.w;
        a2.x += v2.x; a2.y += v2.y; a2.z += v2.z; a2.w += v2.w;
        a3.x += v3.x; a3.y += v3.y; a3.z += v3.z; a3.w += v3.w;
    }
    for (; k < c; k++) {
        unsigned e0 = ids[s+k];
        float4 v0 = e4[(size_t)e0*8 + j];
        a0.x += v0.x; a0.y += v0.y; a0.z += v0.z; a0.w += v0.w;
    }
    float inv = 1.0f / (float)(c > 1 ? c : 1);
    float4 r;
    r.x = (a0.x + a1.x + a2.x + a3.x) * inv;
    r.y = (a0.y + a1.y + a2.y + a3.y) * inv;
    r.z = (a0.z + a1.z + a2.z + a3.z) * inv;
    r.w = (a0.w + a1.w + a2.w + a3.w) * inv;
    out4[(size_t)node * 8 + j] = r;
}

// ---------------- fallback: direct float atomics ----------------
__global__ __launch_bounds__(256) void scatter_atomic_kernel(
    const float4* __restrict__ e4, const int* __restrict__ dst,
    float* __restrict__ sums, int* __restrict__ counts, int total)
{
    int t = blockIdx.x * 256 + threadIdx.x;
    if (t >= total) return;
    int edge = t >> 3;
    int fq = t & 7;
    float4 v = e4[t];
    int d = dst[edge];
    float* o = sums + (size_t)d * D_FEAT + fq * 4;
    atomicAdd(o + 0, v.x);
    atomicAdd(o + 1, v.y);
    atomicAdd(o + 2, v.z);
    atomicAdd(o + 3, v.w);
    if (fq == 0) atomicAdd(counts + d, 1);
}

__global__ __launch_bounds__(256) void finalize_kernel(
    float4* __restrict__ out4, const int* __restrict__ counts, int total)
{
    int t = blockIdx.x * 256 + threadIdx.x;
    if (t >= total) return;
    int node = t >> 3;
    int c = counts[node];
    float inv = 1.0f / (float)(c > 1 ? c : 1);
    float4 v = out4[t];
    v.x *= inv; v.y *= inv; v.z *= inv; v.w *= inv;
    out4[t] = v;
}

extern "C" void kernel_launch(void* const* d_in, const int* in_sizes, int n_in,
                              void* d_out, int out_size, void* d_ws, size_t ws_size,
                              hipStream_t stream) {
    const float4* e4 = (const float4*)d_in[0];
    const int* dst = (const int*)d_in[1];
    int E = in_sizes[0] / D_FEAT;
    int N = out_size / D_FEAT;

    int nblk = (N + SCAN_SPAN - 1) / SCAN_SPAN;

    char* ws = (char*)d_ws;
    // layout: cnt[N] | start[N] | run[N] | bsum[256] | bbase[256] | ids[E]
    size_t need = ((size_t)3 * N + 512) * 4 + (size_t)E * 4;

    if (nblk <= 256 && ws_size >= need) {
        int* cnt      = (int*)ws;
        int* startArr = cnt + N;
        int* run      = startArr + N;
        int* bsum     = run + N;
        int* bbase    = bsum + 256;
        unsigned int* ids = (unsigned int*)(bbase + 256);

        hipMemsetAsync(cnt, 0, (size_t)N * 4, stream);

        int gE = (E + 1023) / 1024;   // 4 edges per thread
        hist_kernel<<<gE, 256, 0, stream>>>(dst, cnt, E);
        scan_block_sums<<<nblk, 256, 0, stream>>>(cnt, bsum, N);
        scan_bases<<<1, 256, 0, stream>>>(bsum, bbase, nblk);
        scan_write<<<nblk, 256, 0, stream>>>(cnt, bbase, startArr, run, N);
        scatter_kernel<<<gE, 256, 0, stream>>>(dst, run, ids, E);
        gather_kernel<<<(N + 31) / 32, 256, 0, stream>>>(e4, ids, startArr, cnt,
                                                         (float4*)d_out, N);
    } else {
        // fallback: direct float atomics
        int* counts = (int*)ws;
        hipMemsetAsync(d_out, 0, (size_t)out_size * sizeof(float), stream);
        hipMemsetAsync(counts, 0, (size_t)N * 4, stream);
        int total = E * (D_FEAT / 4);
        scatter_atomic_kernel<<<(total + 255) / 256, 256, 0, stream>>>(
            e4, dst, (float*)d_out, counts, total);
        int fin = N * (D_FEAT / 4);
        finalize_kernel<<<(fin + 255) / 256, 256, 0, stream>>>(
            (float4*)d_out, counts, fin);
    }
}